// Round 10
// baseline (641.819 us; speedup 1.0000x reference)
//
#include <hip/hip_runtime.h>
#include <math.h>

#define BB 8
#define MTOK 768
#define NTOK 128
#define LTOK 64
#define TT 960          // MTOK+NTOK+LTOK
#define BT 7680         // BB*TT
#define DD 256
#define HH 8
#define HD 32
#define KNN 32
#define FFD 1024
#define NLAYERS 4
#define SCALE_ATT 0.17677669529663687f  // 1/sqrt(32)

typedef __attribute__((ext_vector_type(8))) short bfrag_t;   // 8 bf16 (4 VGPRs)
typedef __attribute__((ext_vector_type(4))) float accfrag_t; // 4 fp32 acc

__device__ __forceinline__ float b2f(unsigned short u) {
  union { unsigned int i; float f; } c; c.i = ((unsigned int)u) << 16; return c.f;
}
__device__ __forceinline__ unsigned short f2b(float f) {
  union { float f; unsigned int i; } c; c.f = f;
  return (unsigned short)((c.i + 0x7fffu + ((c.i >> 16) & 1u)) >> 16);
}
__device__ __forceinline__ float load_elem(const void* p, size_t i, int f) {
  return f ? b2f(((const unsigned short*)p)[i]) : ((const float*)p)[i];
}
// scene->XCD swizzle: blocks land on XCD (blockIdx % 8); keep scene b on XCD b.
__device__ __forceinline__ int swiz_m0(int blk)  { return (blk & 7) * TT + (blk >> 3) * 32; } // 240 blocks
__device__ __forceinline__ int swiz_tok(int blk) { return (blk & 7) * TT + (blk >> 3); }      // 7680 blocks

// ---------------- dtype detector: bf16 -> flag=1, fp32 -> flag=0 ----------------
__global__ __launch_bounds__(256)
void detect_kernel(const void* tok, int* flag) {
  __shared__ int cnt;
  if (threadIdx.x == 0) cnt = 0;
  __syncthreads();
  const unsigned short* u = (const unsigned short*)tok;
  int ok = 0;
  for (int i = threadIdx.x; i < 1024; i += 256) {
    int e = (u[i] >> 7) & 0xFF;
    if (e >= 100 && e <= 140) ok++;
  }
  atomicAdd(&cnt, ok);
  __syncthreads();
  if (threadIdx.x == 0) *flag = (cnt >= 922) ? 1 : 0;
}

// ---------------- positions + params -> fp32 (merged) ----------------
#define FB_BQ 0
#define FB_BK 1024
#define FB_BV 2048
#define FB_BO 3072
#define FB_B1 4096
#define FB_B2 8192
#define FB_LN1S 9216
#define FB_LN1B 10240
#define FB_LN2S 11264
#define FB_LN2B 12288
#define FB_TOTAL 13312
struct ParamSrc { const void* p[13]; };
__global__ __launch_bounds__(256)
void conv_misc_kernel(ParamSrc ps, const int* flag, float* __restrict__ dst,
                      float* __restrict__ posf) {
  int f = *flag;
  if (blockIdx.x < BB) {
    int b = blockIdx.x;
    for (int t = threadIdx.x; t < TT * 2; t += 256) {
      int tok = t >> 1, c = t & 1;
      const void* p; size_t idx;
      if (tok < MTOK)             { p = ps.p[10]; idx = (size_t)(b * MTOK + tok) * 2 + c; }
      else if (tok < MTOK + NTOK) { p = ps.p[11]; idx = (size_t)(b * NTOK + tok - MTOK) * 2 + c; }
      else                        { p = ps.p[12]; idx = (size_t)(b * LTOK + tok - MTOK - NTOK) * 2 + c; }
      posf[((size_t)b * TT + tok) * 2 + c] = load_elem(p, idx, f);
    }
    return;
  }
  int i = (blockIdx.x - BB) * 256 + threadIdx.x;
  if (i >= FB_TOTAL) return;
  int src; size_t off;
  if (i < 4096)      { src = i >> 10;              off = i & 1023; }
  else if (i < 8192) { src = 4;                    off = i - 4096; }
  else               { src = 5 + ((i - 8192) >> 10); off = (i - 8192) & 1023; }
  dst[i] = load_elem(ps.p[src], off, f);
}

// ---------------- all weight transposes in ONE kernel ----------------
struct WSrc { const void* s[6]; unsigned short* d[6]; };
__global__ __launch_bounds__(256)
void convT_all_kernel(WSrc w, const int* flag) {
  __shared__ unsigned short tile[32][33];
  int f = *flag;
  int id = blockIdx.x;
  int op, R, C; size_t dstStride;
  int tilesXY, layer, txy;
  if (id < 1024)      { op = id >> 8; id &= 255; R = 256; C = 256;
                        dstStride = (op < 3) ? (size_t)3 * DD * DD : (size_t)DD * DD;
                        tilesXY = 64; }
  else if (id < 2048) { op = 4; id -= 1024; R = 256; C = 1024; dstStride = (size_t)DD * FFD; tilesXY = 256; }
  else                { op = 5; id -= 2048; R = 1024; C = 256; dstStride = (size_t)DD * FFD; tilesXY = 256; }
  layer = id / tilesXY; txy = id % tilesXY;
  int tilesX = C >> 5;
  int c0 = (txy % tilesX) * 32, r0 = (txy / tilesX) * 32;
  const void* src = w.s[op];
  unsigned short* d = w.d[op] + (size_t)layer * dstStride
                    + ((op > 0 && op < 3) ? (size_t)op * DD * DD : 0);
  size_t sbase = (size_t)layer * R * C;
  int tx = threadIdx.x & 31, ty = threadIdx.x >> 5;
  for (int rr = ty; rr < 32; rr += 8) {
    size_t si = sbase + (size_t)(r0 + rr) * C + c0 + tx;
    tile[rr][tx] = f ? ((const unsigned short*)src)[si] : f2b(((const float*)src)[si]);
  }
  __syncthreads();
  for (int cc = ty; cc < 32; cc += 8)
    d[(size_t)(c0 + cc) * R + r0 + tx] = tile[tx][cc];
}

// ---------------- prep: positional embedding + stream init ----------------
__global__ __launch_bounds__(256)
void prep_kernel(const void* mt, const void* at, const void* lt,
                 const float* __restrict__ posf, const int* flag,
                 unsigned short* __restrict__ pe_b, float* __restrict__ out_f,
                 unsigned short* __restrict__ out_b, unsigned short* __restrict__ qk_b) {
  int n = swiz_tok(blockIdx.x), d = threadIdx.x;
  int b = n / TT, t = n - b * TT;
  int f = *flag;
  const void* src; size_t si;
  if (t < MTOK)              { src = mt; si = (size_t)(b * MTOK + t) * DD + d; }
  else if (t < MTOK + NTOK)  { src = at; si = (size_t)(b * NTOK + (t - MTOK)) * DD + d; }
  else                       { src = lt; si = (size_t)(b * LTOK + (t - MTOK - NTOK)) * DD + d; }
  float x = load_elem(src, si, f);
  float px = posf[((size_t)b * TT + t) * 2 + 0];
  float py = posf[((size_t)b * TT + t) * 2 + 1];
  float coord = (d < 128) ? py : px;
  int j = d & 127;
  float expo = (float)(2 * (j >> 1)) / 128.0f;
  float dim_t = powf(10000.0f, expo);
  float e = coord * 6.283185307179586f / dim_t;
  float p = (j & 1) ? cosf(e) : sinf(e);
  size_t o = (size_t)n * DD + d;
  pe_b[o] = f2b(p);
  out_f[o] = x;
  out_b[o] = f2b(x);
  qk_b[o] = f2b(x + p);
}

// ---------------- KNN: wave-per-query, 32-bit keys, implicit indices ----------------
__global__ __launch_bounds__(256)
void knn_kernel(const float* __restrict__ posf, int* __restrict__ idx_out) {
  __shared__ float sx[TT], sy[TT];
  int b = blockIdx.x & 7;
  int qbase = (blockIdx.x >> 3) * 4;
  for (int t = threadIdx.x; t < TT; t += 256) {
    sx[t] = posf[((size_t)b * TT + t) * 2 + 0];
    sy[t] = posf[((size_t)b * TT + t) * 2 + 1];
  }
  __syncthreads();
  int wave = threadIdx.x >> 6, lane = threadIdx.x & 63;
  int t = qbase + wave;
  float qx = sx[t], qy = sy[t];
#define MK(c) ({ int j = (c) * 64 + lane;                                    \
                 float dx = qx - sx[j], dy = qy - sy[j];                     \
                 float d2 = __fadd_rn(__fmul_rn(dx, dx), __fmul_rn(dy, dy)); \
                 __float_as_uint(d2); })
  unsigned d0 = MK(0), d1 = MK(1), d2_ = MK(2), d3 = MK(3), d4 = MK(4);
  unsigned d5 = MK(5), d6 = MK(6), d7 = MK(7), d8 = MK(8), d9 = MK(9);
  unsigned d10 = MK(10), d11 = MK(11), d12 = MK(12), d13 = MK(13), d14 = MK(14);
#undef MK
  unsigned res_i = 0;
  for (int i = 0; i < KNN; i++) {
    unsigned bv = d0, bc = 0;
#define UPD(dc, c) { if ((dc) < bv) { bv = (dc); bc = (c); } }
    UPD(d1, 1)  UPD(d2_, 2)  UPD(d3, 3)  UPD(d4, 4)  UPD(d5, 5)
    UPD(d6, 6)  UPD(d7, 7)   UPD(d8, 8)  UPD(d9, 9)  UPD(d10, 10)
    UPD(d11, 11) UPD(d12, 12) UPD(d13, 13) UPD(d14, 14)
#undef UPD
    unsigned gi = (bc << 6) + (unsigned)lane;
#pragma unroll
    for (int o = 32; o > 0; o >>= 1) {
      unsigned od = (unsigned)__shfl_xor((int)bv, o);
      unsigned oi = (unsigned)__shfl_xor((int)gi, o);
      bool take = (od < bv) || (od == bv && oi < gi);
      bv = take ? od : bv;
      gi = take ? oi : gi;
    }
    res_i = ((unsigned)lane == (unsigned)i) ? gi : res_i;
    bool wl = ((unsigned)lane == (gi & 63u));
    unsigned s = gi >> 6;
    d0  = (wl && s == 0)  ? 0xFFFFFFFFu : d0;
    d1  = (wl && s == 1)  ? 0xFFFFFFFFu : d1;
    d2_ = (wl && s == 2)  ? 0xFFFFFFFFu : d2_;
    d3  = (wl && s == 3)  ? 0xFFFFFFFFu : d3;
    d4  = (wl && s == 4)  ? 0xFFFFFFFFu : d4;
    d5  = (wl && s == 5)  ? 0xFFFFFFFFu : d5;
    d6  = (wl && s == 6)  ? 0xFFFFFFFFu : d6;
    d7  = (wl && s == 7)  ? 0xFFFFFFFFu : d7;
    d8  = (wl && s == 8)  ? 0xFFFFFFFFu : d8;
    d9  = (wl && s == 9)  ? 0xFFFFFFFFu : d9;
    d10 = (wl && s == 10) ? 0xFFFFFFFFu : d10;
    d11 = (wl && s == 11) ? 0xFFFFFFFFu : d11;
    d12 = (wl && s == 12) ? 0xFFFFFFFFu : d12;
    d13 = (wl && s == 13) ? 0xFFFFFFFFu : d13;
    d14 = (wl && s == 14) ? 0xFFFFFFFFu : d14;
  }
  if (lane < KNN)
    idx_out[((size_t)(b * TT + t)) * KNN + lane] = b * TT + (int)res_i;
}

// ---------------- GEMM core: direct global->VGPR, barrier-free ----------------
// Each lane loads exactly its MFMA fragments (16B) from global; no LDS, no
// __syncthreads in the K-loop. B is L2-hot (shared by 240 blocks), A is
// L1-hot (4 waves share rows). Compiler pipelines loads over MFMAs.
template<int KDIM>
__device__ __forceinline__ void gemm_direct(const unsigned short* __restrict__ A,
                                            const unsigned short* __restrict__ Bt, // [256][KDIM]
                                            int m0, accfrag_t (&acc)[2][4]) {
  const int lane = threadIdx.x & 63, wave = threadIdx.x >> 6;
  const int l16 = lane & 15, lq = lane >> 4;
  accfrag_t z = {0.f, 0.f, 0.f, 0.f};
#pragma unroll
  for (int mt = 0; mt < 2; mt++)
#pragma unroll
    for (int nt = 0; nt < 4; nt++) acc[mt][nt] = z;
  const unsigned short* ap0 = A + (size_t)(m0 + l16) * KDIM + lq * 8;
  const unsigned short* ap1 = ap0 + (size_t)16 * KDIM;
  const unsigned short* bp  = Bt + (size_t)(wave * 64 + l16) * KDIM + lq * 8;
#pragma unroll 2
  for (int k0 = 0; k0 < KDIM; k0 += 64) {
    bfrag_t a00 = *(const bfrag_t*)(ap0 + k0);
    bfrag_t a01 = *(const bfrag_t*)(ap0 + k0 + 32);
    bfrag_t a10 = *(const bfrag_t*)(ap1 + k0);
    bfrag_t a11 = *(const bfrag_t*)(ap1 + k0 + 32);
#pragma unroll
    for (int nt = 0; nt < 4; nt++) {
      bfrag_t b0 = *(const bfrag_t*)(bp + (size_t)(nt * 16) * KDIM + k0);
      bfrag_t b1 = *(const bfrag_t*)(bp + (size_t)(nt * 16) * KDIM + k0 + 32);
      acc[0][nt] = __builtin_amdgcn_mfma_f32_16x16x32_bf16(a00, b0, acc[0][nt], 0, 0, 0);
      acc[1][nt] = __builtin_amdgcn_mfma_f32_16x16x32_bf16(a10, b0, acc[1][nt], 0, 0, 0);
      acc[0][nt] = __builtin_amdgcn_mfma_f32_16x16x32_bf16(a01, b1, acc[0][nt], 0, 0, 0);
      acc[1][nt] = __builtin_amdgcn_mfma_f32_16x16x32_bf16(a11, b1, acc[1][nt], 0, 0, 0);
    }
  }
}

// ---------------- fused QKV GEMM (grid.y = 0:Q 1:K 2:V), no LDS ----------------
__global__ __launch_bounds__(256)
void gemm_qkv_kernel(const unsigned short* __restrict__ Aqk,
                     const unsigned short* __restrict__ Aout,
                     const unsigned short* __restrict__ WT3,
                     const float* __restrict__ bq,
                     const float* __restrict__ bk,
                     const float* __restrict__ bv,
                     unsigned short* __restrict__ QKV) {
  int m0 = swiz_m0(blockIdx.x);
  int sel = blockIdx.y;
  const unsigned short* A = (sel < 2) ? Aqk : Aout;
  const unsigned short* Bt = WT3 + (size_t)sel * (DD * DD);
  const float* bias = (sel == 0) ? bq : (sel == 1) ? bk : bv;
  unsigned short* C = QKV + (size_t)sel * BT * DD;
  accfrag_t acc[2][4];
  gemm_direct<DD>(A, Bt, m0, acc);
  const int lane = threadIdx.x & 63, wave = threadIdx.x >> 6;
  const int l16 = lane & 15, lq = lane >> 4;
#pragma unroll
  for (int mt = 0; mt < 2; mt++)
#pragma unroll
    for (int nt = 0; nt < 4; nt++) {
      int col = wave * 64 + nt * 16 + l16;
      float bval = bias[col];
#pragma unroll
      for (int r = 0; r < 4; r++) {
        int row = m0 + mt * 16 + lq * 4 + r;
        C[(size_t)row * DD + col] = f2b(acc[mt][nt][r] + bval);
      }
    }
}

// ---------------- KNN attention (one block per token, scene->XCD swizzled) ----------------
__global__ __launch_bounds__(256)
void attn_kernel(const unsigned short* __restrict__ QKV,
                 const int* __restrict__ idx,
                 unsigned short* __restrict__ aout) {
  __shared__ unsigned short kn[KNN][DD + 8];
  __shared__ unsigned short vn[KNN][DD + 8];
  __shared__ float qs[DD];
  __shared__ float att[HH][KNN];
  __shared__ int nb[KNN];
  const unsigned short* Q = QKV;
  const unsigned short* K = QKV + (size_t)BT * DD;
  const unsigned short* V = QKV + 2 * (size_t)BT * DD;
  int n = swiz_tok(blockIdx.x), tid = threadIdx.x;
  if (tid < KNN) nb[tid] = idx[n * KNN + tid];
  qs[tid] = b2f(Q[(size_t)n * DD + tid]);
  __syncthreads();
#pragma unroll
  for (int p = 0; p < 4; p++) {
    int e = p * 256 + tid;
    int r = e >> 5, c8 = (e & 31) * 8;
    int srow = nb[r];
    *(uint4*)(&kn[r][c8]) = *(const uint4*)(K + (size_t)srow * DD + c8);
    *(uint4*)(&vn[r][c8]) = *(const uint4*)(V + (size_t)srow * DD + c8);
  }
  __syncthreads();
  int h = tid >> 5, kk = tid & 31;
  float dot = 0.0f;
#pragma unroll
  for (int d = 0; d < HD; d++) dot += qs[h * HD + d] * b2f(kn[kk][h * HD + d]);
  float sc = dot * SCALE_ATT;
  float mx = sc;
#pragma unroll
  for (int o = 16; o > 0; o >>= 1) mx = fmaxf(mx, __shfl_xor(mx, o, 32));
  float ex = expf(sc - mx);
  float sm = ex;
#pragma unroll
  for (int o = 16; o > 0; o >>= 1) sm += __shfl_xor(sm, o, 32);
  att[h][kk] = ex / sm;
  __syncthreads();
  int d = kk;
  float oacc = 0.0f;
#pragma unroll
  for (int k2 = 0; k2 < KNN; k2++) oacc += att[h][k2] * b2f(vn[k2][h * HD + d]);
  aout[(size_t)n * DD + tid] = f2b(oacc);
}

// ---------------- MEGA: Wo+LN1+FFN1+ReLU+FFN2+LN2 (row-local fusion) ----------------
struct MegaSmem {
  float Cs[32][260];            // 33.3 KB epilogue scratch
  unsigned short xs[32][264];   // 16.9 KB LN1 output bf16 (pad 264 -> banks spread)
};

template<bool LAST>
__global__ __launch_bounds__(256)
void mega_kernel(const unsigned short* __restrict__ attnout,
                 const unsigned short* __restrict__ WoT,
                 const unsigned short* __restrict__ W1T,
                 const unsigned short* __restrict__ W2T,
                 const float* __restrict__ bo,  const float* __restrict__ b1,
                 const float* __restrict__ b2,
                 const float* __restrict__ ln1s, const float* __restrict__ ln1b,
                 const float* __restrict__ ln2s, const float* __restrict__ ln2b,
                 float* __restrict__ out_f, unsigned short* __restrict__ out_b,
                 unsigned short* __restrict__ qk_b,
                 const unsigned short* __restrict__ pe_b,
                 unsigned short* __restrict__ hbuf,
                 void* __restrict__ dout, const int* __restrict__ flag) {
  __shared__ MegaSmem sh;
  const int m0 = swiz_m0(blockIdx.x);
  const int lane = threadIdx.x & 63, wave = threadIdx.x >> 6;
  const int l16 = lane & 15, lq = lane >> 4;
  const float inv = 1.0f / 256.0f;
  accfrag_t acc[2][4];
  float yreg[8][4];   // LN1 output, fp32, in the LN-epilogue layout

  // ---- stage A: Wo GEMM (direct) + resid + LN1 ----
  gemm_direct<DD>(attnout, WoT, m0, acc);
#pragma unroll
  for (int mt = 0; mt < 2; mt++)
#pragma unroll
    for (int nt = 0; nt < 4; nt++) {
      int col = wave * 64 + nt * 16 + l16;
      float bval = bo[col];
#pragma unroll
      for (int r = 0; r < 4; r++) {
        int lrow = mt * 16 + lq * 4 + r;
        sh.Cs[lrow][col] = acc[mt][nt][r] + bval + out_f[(size_t)(m0 + lrow) * DD + col];
      }
    }
  __syncthreads();
#pragma unroll
  for (int rr = 0; rr < 8; rr++) {
    int lrow = wave * 8 + rr;
    const float4 x = *(const float4*)(&sh.Cs[lrow][lane * 4]);
    float s  = x.x + x.y + x.z + x.w;
    float s2 = x.x * x.x + x.y * x.y + x.z * x.z + x.w * x.w;
#pragma unroll
    for (int o = 32; o > 0; o >>= 1) { s += __shfl_xor(s, o); s2 += __shfl_xor(s2, o); }
    float mu = s * inv;
    float var = s2 * inv - mu * mu;
    float rstd = 1.0f / sqrtf(fmaxf(var, 0.0f) + 1e-5f);
    int c0 = lane * 4;
    float xv[4] = {x.x, x.y, x.z, x.w};
    unsigned short pk[4];
#pragma unroll
    for (int c = 0; c < 4; c++) {
      float y = (xv[c] - mu) * rstd * ln1s[c0 + c] + ln1b[c0 + c];
      yreg[rr][c] = y;
      pk[c] = f2b(y);
    }
    *(uint2*)(&sh.xs[lrow][c0]) = make_uint2(
        (unsigned)pk[0] | ((unsigned)pk[1] << 16),
        (unsigned)pk[2] | ((unsigned)pk[3] << 16));
  }
  __syncthreads();

  // ---- stage B: h = relu(x @ W1 + b1); A from xs (LDS), B direct ----
#pragma unroll 1
  for (int c4 = 0; c4 < 4; c4++) {
    const unsigned short* bp = W1T + (size_t)(c4 * 256 + wave * 64 + l16) * DD + lq * 8;
    accfrag_t z = {0.f, 0.f, 0.f, 0.f};
#pragma unroll
    for (int mt = 0; mt < 2; mt++)
#pragma unroll
      for (int nt = 0; nt < 4; nt++) acc[mt][nt] = z;
#pragma unroll 2
    for (int k0 = 0; k0 < DD; k0 += 64) {
      bfrag_t a00 = *(const bfrag_t*)(&sh.xs[l16][k0 + lq * 8]);
      bfrag_t a01 = *(const bfrag_t*)(&sh.xs[l16][k0 + 32 + lq * 8]);
      bfrag_t a10 = *(const bfrag_t*)(&sh.xs[16 + l16][k0 + lq * 8]);
      bfrag_t a11 = *(const bfrag_t*)(&sh.xs[16 + l16][k0 + 32 + lq * 8]);
#pragma unroll
      for (int nt = 0; nt < 4; nt++) {
        bfrag_t b0 = *(const bfrag_t*)(bp + (size_t)(nt * 16) * DD + k0);
        bfrag_t b1 = *(const bfrag_t*)(bp + (size_t)(nt * 16) * DD + k0 + 32);
        acc[0][nt] = __builtin_amdgcn_mfma_f32_16x16x32_bf16(a00, b0, acc[0][nt], 0, 0, 0);
        acc[1][nt] = __builtin_amdgcn_mfma_f32_16x16x32_bf16(a10, b0, acc[1][nt], 0, 0, 0);
        acc[0][nt] = __builtin_amdgcn_mfma_f32_16x16x32_bf16(a01, b1, acc[0][nt], 0, 0, 0);
        acc[1][nt] = __builtin_amdgcn_mfma_f32_16x16x32_bf16(a11, b1, acc[1][nt], 0, 0, 0);
      }
    }
#pragma unroll
    for (int mt = 0; mt < 2; mt++)
#pragma unroll
      for (int nt = 0; nt < 4; nt++) {
        int col = wave * 64 + nt * 16 + l16;
        float bval = b1[c4 * 256 + col];
#pragma unroll
        for (int r = 0; r < 4; r++) {
          int row = m0 + mt * 16 + lq * 4 + r;
          hbuf[(size_t)row * FFD + c4 * 256 + col] = f2b(fmaxf(acc[mt][nt][r] + bval, 0.0f));
        }
      }
  }
  __syncthreads();   // drain hbuf stores before cross-thread reads (vmcnt(0) at barrier)

  // ---- stage C: FFN2 GEMM (direct) + resid(yreg) + LN2 ----
  gemm_direct<FFD>(hbuf, W2T, m0, acc);
  __syncthreads();   // Cs reuse
#pragma unroll
  for (int mt = 0; mt < 2; mt++)
#pragma unroll
    for (int nt = 0; nt < 4; nt++) {
      int col = wave * 64 + nt * 16 + l16;
      float bval = b2[col];
#pragma unroll
      for (int r = 0; r < 4; r++) {
        int lrow = mt * 16 + lq * 4 + r;
        sh.Cs[lrow][col] = acc[mt][nt][r] + bval;
      }
    }
  __syncthreads();
  const int f = *flag;
#pragma unroll
  for (int rr = 0; rr < 8; rr++) {
    int lrow = wave * 8 + rr;
    int grow = m0 + lrow;
    const float4 x = *(const float4*)(&sh.Cs[lrow][lane * 4]);
    float xv[4] = {x.x + yreg[rr][0], x.y + yreg[rr][1], x.z + yreg[rr][2], x.w + yreg[rr][3]};
    float s = 0.f, s2 = 0.f;
#pragma unroll
    for (int c = 0; c < 4; c++) { s += xv[c]; s2 += xv[c] * xv[c]; }
#pragma unroll
    for (int o = 32; o > 0; o >>= 1) { s += __shfl_xor(s, o); s2 += __shfl_xor(s2, o); }
    float mu = s * inv;
    float var = s2 * inv - mu * mu;
    float rstd = 1.0f / sqrtf(fmaxf(var, 0.0f) + 1e-5f);
    int c0 = lane * 4;
    float ys[4];
#pragma unroll
    for (int c = 0; c < 4; c++)
      ys[c] = (xv[c] - mu) * rstd * ln2s[c0 + c] + ln2b[c0 + c];
    if (!LAST) {
      *(float4*)(&out_f[(size_t)grow * DD + c0]) = make_float4(ys[0], ys[1], ys[2], ys[3]);
#pragma unroll
      for (int c = 0; c < 4; c++) {
        out_b[(size_t)grow * DD + c0 + c] = f2b(ys[c]);
        qk_b[(size_t)grow * DD + c0 + c] = f2b(ys[c] + b2f(pe_b[(size_t)grow * DD + c0 + c]));
      }
    } else {
      int b = grow / TT, t = grow - b * TT;
      size_t o;
      if (t < MTOK)             o = (size_t)(b * MTOK + t) * DD + c0;
      else if (t < MTOK + NTOK) o = (size_t)BB * MTOK * DD + (size_t)(b * NTOK + (t - MTOK)) * DD + c0;
      else                      o = (size_t)BB * MTOK * DD + (size_t)BB * NTOK * DD
                                  + (size_t)(b * LTOK + (t - MTOK - NTOK)) * DD + c0;
#pragma unroll
      for (int c = 0; c < 4; c++) {
        if (f) ((unsigned short*)dout)[o + c] = f2b(ys[c]);
        else   ((float*)dout)[o + c] = ys[c];
      }
    }
  }
}

// ---------------- launcher ----------------
extern "C" void kernel_launch(void* const* d_in, const int* in_sizes, int n_in,
                              void* d_out, int out_size, void* d_ws, size_t ws_size,
                              hipStream_t stream) {
  const void* map_tok   = d_in[0];
  const void* agent_tok = d_in[1];
  const void* light_tok = d_in[2];
  const void* map_pos   = d_in[3];
  const void* agent_pos = d_in[4];
  const void* light_pos = d_in[5];
  const void* Wq  = d_in[9];
  const void* bq  = d_in[10];
  const void* Wk  = d_in[11];
  const void* bk  = d_in[12];
  const void* Wv  = d_in[13];
  const void* bv  = d_in[14];
  const void* Wo  = d_in[15];
  const void* bo  = d_in[16];
  const void* W1  = d_in[17];
  const void* b1  = d_in[18];
  const void* W2  = d_in[19];
  const void* b2  = d_in[20];
  const void* ln1s = d_in[21];
  const void* ln1b = d_in[22];
  const void* ln2s = d_in[23];
  const void* ln2b = d_in[24];

  size_t off = 0;
  char* base = (char*)d_ws;
  auto take = [&](size_t bytes) { char* p = base + off; off += (bytes + 255) & ~(size_t)255; return (void*)p; };
  int*   flag  = (int*)take(256);
  float* posf  = (float*)take((size_t)BT * 2 * 4);
  float* pbuf  = (float*)take((size_t)FB_TOTAL * 4);
  unsigned short* pe_b = (unsigned short*)take((size_t)BT * DD * 2);
  float* out_f = (float*)take((size_t)BT * DD * 4);
  unsigned short* out_b = (unsigned short*)take((size_t)BT * DD * 2);
  unsigned short* qk_b  = (unsigned short*)take((size_t)BT * DD * 2);
  unsigned short* QKV   = (unsigned short*)take((size_t)3 * BT * DD * 2);
  unsigned short* attnout = QKV;            // overwrites Q region (per-block self-write, safe)
  unsigned short* hbuf  = (unsigned short*)take((size_t)BT * FFD * 2);
  int* idxb = (int*)take((size_t)BT * KNN * 4);
  unsigned short* WqkvT = (unsigned short*)take((size_t)NLAYERS * 3 * DD * DD * 2);
  unsigned short* WoT   = (unsigned short*)take((size_t)NLAYERS * DD * DD * 2);
  unsigned short* W1T   = (unsigned short*)take((size_t)NLAYERS * DD * FFD * 2);
  unsigned short* W2T   = (unsigned short*)take((size_t)NLAYERS * DD * FFD * 2);

  detect_kernel<<<1, 256, 0, stream>>>(map_tok, flag);
  ParamSrc ps; ps.p[0]=bq; ps.p[1]=bk; ps.p[2]=bv; ps.p[3]=bo; ps.p[4]=b1;
  ps.p[5]=b2; ps.p[6]=ln1s; ps.p[7]=ln1b; ps.p[8]=ln2s; ps.p[9]=ln2b;
  ps.p[10]=map_pos; ps.p[11]=agent_pos; ps.p[12]=light_pos;
  conv_misc_kernel<<<BB + (FB_TOTAL + 255) / 256, 256, 0, stream>>>(ps, flag, pbuf, posf);

  WSrc w;
  w.s[0]=Wq; w.s[1]=Wk; w.s[2]=Wv; w.s[3]=Wo; w.s[4]=W1; w.s[5]=W2;
  w.d[0]=WqkvT; w.d[1]=WqkvT; w.d[2]=WqkvT; w.d[3]=WoT; w.d[4]=W1T; w.d[5]=W2T;
  convT_all_kernel<<<3072, 256, 0, stream>>>(w, flag);

  prep_kernel<<<BT, 256, 0, stream>>>(map_tok, agent_tok, light_tok, posf, flag,
                                      pe_b, out_f, out_b, qk_b);
  knn_kernel<<<1920, 256, 0, stream>>>(posf, idxb);

  const int RB = BT / 32; // 240 row blocks
  for (int l = 0; l < NLAYERS; l++) {
    gemm_qkv_kernel<<<dim3(RB, 3), 256, 0, stream>>>(
        qk_b, out_b, WqkvT + (size_t)l * 3 * DD * DD,
        pbuf + FB_BQ + l * DD, pbuf + FB_BK + l * DD, pbuf + FB_BV + l * DD, QKV);
    attn_kernel<<<BT, 256, 0, stream>>>(QKV, idxb, attnout);
    if (l < NLAYERS - 1) {
      mega_kernel<false><<<RB, 256, 0, stream>>>(
          attnout, WoT + (size_t)l * DD * DD, W1T + (size_t)l * DD * FFD, W2T + (size_t)l * DD * FFD,
          pbuf + FB_BO + l * DD, pbuf + FB_B1 + l * FFD, pbuf + FB_B2 + l * DD,
          pbuf + FB_LN1S + l * DD, pbuf + FB_LN1B + l * DD,
          pbuf + FB_LN2S + l * DD, pbuf + FB_LN2B + l * DD,
          out_f, out_b, qk_b, pe_b, hbuf, d_out, flag);
    } else {
      mega_kernel<true><<<RB, 256, 0, stream>>>(
          attnout, WoT + (size_t)l * DD * DD, W1T + (size_t)l * DD * FFD, W2T + (size_t)l * DD * FFD,
          pbuf + FB_BO + l * DD, pbuf + FB_B1 + l * FFD, pbuf + FB_B2 + l * DD,
          pbuf + FB_LN1S + l * DD, pbuf + FB_LN1B + l * DD,
          pbuf + FB_LN2S + l * DD, pbuf + FB_LN2B + l * DD,
          out_f, out_b, qk_b, pe_b, hbuf, d_out, flag);
    }
  }
}

// Round 12
// 559.538 us; speedup vs baseline: 1.1471x; 1.1471x over previous
//
#include <hip/hip_runtime.h>
#include <math.h>

#define BB 8
#define MTOK 768
#define NTOK 128
#define LTOK 64
#define TT 960          // MTOK+NTOK+LTOK
#define BT 7680         // BB*TT
#define DD 256
#define HH 8
#define HD 32
#define KNN 32
#define FFD 1024
#define NLAYERS 4
#define SCALE_ATT 0.17677669529663687f  // 1/sqrt(32)

typedef __attribute__((ext_vector_type(8))) short bfrag_t;   // 8 bf16 (4 VGPRs)
typedef __attribute__((ext_vector_type(4))) float accfrag_t; // 4 fp32 acc

__device__ __forceinline__ float b2f(unsigned short u) {
  union { unsigned int i; float f; } c; c.i = ((unsigned int)u) << 16; return c.f;
}
__device__ __forceinline__ unsigned short f2b(float f) {
  union { float f; unsigned int i; } c; c.f = f;
  return (unsigned short)((c.i + 0x7fffu + ((c.i >> 16) & 1u)) >> 16);
}
__device__ __forceinline__ float load_elem(const void* p, size_t i, int f) {
  return f ? b2f(((const unsigned short*)p)[i]) : ((const float*)p)[i];
}
// fragment-packed layout: element (row,k[col]) of [R x K] ->
//   ((row/16)*NKS + k/32)*512 + (((k>>3)&3)*16 + row%16)*8 + k%8
__device__ __forceinline__ size_t pk_addr(int row, int col, int nks) {
  return ((size_t)((row >> 4) * nks + (col >> 5)) << 9)
       + (size_t)(((((col >> 3) & 3) << 4) + (row & 15)) * 8 + (col & 7));
}
__device__ __forceinline__ uint4 pack8(const float* v) {
  uint4 u;
  u.x = (unsigned)f2b(v[0]) | ((unsigned)f2b(v[1]) << 16);
  u.y = (unsigned)f2b(v[2]) | ((unsigned)f2b(v[3]) << 16);
  u.z = (unsigned)f2b(v[4]) | ((unsigned)f2b(v[5]) << 16);
  u.w = (unsigned)f2b(v[6]) | ((unsigned)f2b(v[7]) << 16);
  return u;
}
// scene->XCD swizzle
__device__ __forceinline__ int swiz_m0(int blk)  { return (blk & 7) * TT + (blk >> 3) * 32; }
__device__ __forceinline__ int swiz_tok(int blk) { return (blk & 7) * TT + (blk >> 3); }

// ---------------- dtype detector ----------------
__global__ __launch_bounds__(256)
void detect_kernel(const void* tok, int* flag) {
  __shared__ int cnt;
  if (threadIdx.x == 0) cnt = 0;
  __syncthreads();
  const unsigned short* u = (const unsigned short*)tok;
  int ok = 0;
  for (int i = threadIdx.x; i < 1024; i += 256) {
    int e = (u[i] >> 7) & 0xFF;
    if (e >= 100 && e <= 140) ok++;
  }
  atomicAdd(&cnt, ok);
  __syncthreads();
  if (threadIdx.x == 0) *flag = (cnt >= 922) ? 1 : 0;
}

// ---------------- positions + params -> fp32 ----------------
#define FB_BQ 0
#define FB_BK 1024
#define FB_BV 2048
#define FB_BO 3072
#define FB_B1 4096
#define FB_B2 8192
#define FB_LN1S 9216
#define FB_LN1B 10240
#define FB_LN2S 11264
#define FB_LN2B 12288
#define FB_TOTAL 13312
struct ParamSrc { const void* p[13]; };
__global__ __launch_bounds__(256)
void conv_misc_kernel(ParamSrc ps, const int* flag, float* __restrict__ dst,
                      float* __restrict__ posf) {
  int f = *flag;
  if (blockIdx.x < BB) {
    int b = blockIdx.x;
    for (int t = threadIdx.x; t < TT * 2; t += 256) {
      int tok = t >> 1, c = t & 1;
      const void* p; size_t idx;
      if (tok < MTOK)             { p = ps.p[10]; idx = (size_t)(b * MTOK + tok) * 2 + c; }
      else if (tok < MTOK + NTOK) { p = ps.p[11]; idx = (size_t)(b * NTOK + tok - MTOK) * 2 + c; }
      else                        { p = ps.p[12]; idx = (size_t)(b * LTOK + tok - MTOK - NTOK) * 2 + c; }
      posf[((size_t)b * TT + tok) * 2 + c] = load_elem(p, idx, f);
    }
    return;
  }
  int i = (blockIdx.x - BB) * 256 + threadIdx.x;
  if (i >= FB_TOTAL) return;
  int src; size_t off;
  if (i < 4096)      { src = i >> 10;              off = i & 1023; }
  else if (i < 8192) { src = 4;                    off = i - 4096; }
  else               { src = 5 + ((i - 8192) >> 10); off = (i - 8192) & 1023; }
  dst[i] = load_elem(ps.p[src], off, f);
}

// ---------------- pack all weights into fragment order ----------------
struct PackSrc { const void* s[6]; };
__global__ __launch_bounds__(256)
void packW_kernel(PackSrc w, const int* flag,
                  unsigned short* __restrict__ Wqkvpk, unsigned short* __restrict__ Wopk,
                  unsigned short* __restrict__ W1pk, unsigned short* __restrict__ W2pk) {
  int f = *flag;
  int id = blockIdx.x * 256 + threadIdx.x;
  const void* src; unsigned short* dst; int layer, e, K, N;
  if (id < 786432) {                    // Wq,Wk,Wv: 4 layers x 3 x 65536
    layer = id / 196608; int rest = id % 196608; int sel = rest / 65536; e = rest % 65536;
    src = w.s[sel]; dst = Wqkvpk + id; K = 256; N = 256;
  } else if (id < 1048576) {            // Wo
    int off = id - 786432; layer = off / 65536; e = off % 65536;
    src = w.s[3]; dst = Wopk + off; K = 256; N = 256;
  } else if (id < 2097152) {            // W1
    int off = id - 1048576; layer = off / 262144; e = off % 262144;
    src = w.s[4]; dst = W1pk + off; K = 256; N = 1024;
  } else {                              // W2
    int off = id - 2097152; layer = off / 262144; e = off % 262144;
    src = w.s[5]; dst = W2pk + off; K = 1024; N = 256;
  }
  int nks = K >> 5;
  int cb = e / (nks * 512);
  int ks = (e / 512) % nks;
  int lane = (e >> 3) & 63, j = e & 7;
  int col = cb * 16 + (lane & 15);
  int k = ks * 32 + (lane >> 4) * 8 + j;
  size_t si = (size_t)layer * K * N + (size_t)k * N + col;
  *dst = f ? ((const unsigned short*)src)[si] : f2b(((const float*)src)[si]);
}

// ---------------- prep: positional embedding + stream init ----------------
__global__ __launch_bounds__(256)
void prep_kernel(const void* mt, const void* at, const void* lt,
                 const float* __restrict__ posf, const int* flag,
                 unsigned short* __restrict__ pe_b, float* __restrict__ out_f,
                 unsigned short* __restrict__ pk1, unsigned short* __restrict__ qkpk) {
  int n = swiz_tok(blockIdx.x), d = threadIdx.x;
  int b = n / TT, t = n - b * TT;
  int f = *flag;
  const void* src; size_t si;
  if (t < MTOK)              { src = mt; si = (size_t)(b * MTOK + t) * DD + d; }
  else if (t < MTOK + NTOK)  { src = at; si = (size_t)(b * NTOK + (t - MTOK)) * DD + d; }
  else                       { src = lt; si = (size_t)(b * LTOK + (t - MTOK - NTOK)) * DD + d; }
  float x = load_elem(src, si, f);
  float px = posf[((size_t)b * TT + t) * 2 + 0];
  float py = posf[((size_t)b * TT + t) * 2 + 1];
  float coord = (d < 128) ? py : px;
  int j = d & 127;
  float expo = (float)(2 * (j >> 1)) / 128.0f;
  float dim_t = powf(10000.0f, expo);
  float e = coord * 6.283185307179586f / dim_t;
  float p = (j & 1) ? cosf(e) : sinf(e);
  size_t o = (size_t)n * DD + d;
  pe_b[o] = f2b(p);
  out_f[o] = x;
  size_t pa = pk_addr(n, d, 8);
  pk1[pa] = f2b(x);
  qkpk[pa] = f2b(x + p);
}

// ---------------- KNN (unchanged, verified) ----------------
__global__ __launch_bounds__(256)
void knn_kernel(const float* __restrict__ posf, int* __restrict__ idx_out) {
  __shared__ float sx[TT], sy[TT];
  int b = blockIdx.x & 7;
  int qbase = (blockIdx.x >> 3) * 4;
  for (int t = threadIdx.x; t < TT; t += 256) {
    sx[t] = posf[((size_t)b * TT + t) * 2 + 0];
    sy[t] = posf[((size_t)b * TT + t) * 2 + 1];
  }
  __syncthreads();
  int wave = threadIdx.x >> 6, lane = threadIdx.x & 63;
  int t = qbase + wave;
  float qx = sx[t], qy = sy[t];
#define MK(c) ({ int j = (c) * 64 + lane;                                    \
                 float dx = qx - sx[j], dy = qy - sy[j];                     \
                 float d2 = __fadd_rn(__fmul_rn(dx, dx), __fmul_rn(dy, dy)); \
                 __float_as_uint(d2); })
  unsigned d0 = MK(0), d1 = MK(1), d2_ = MK(2), d3 = MK(3), d4 = MK(4);
  unsigned d5 = MK(5), d6 = MK(6), d7 = MK(7), d8 = MK(8), d9 = MK(9);
  unsigned d10 = MK(10), d11 = MK(11), d12 = MK(12), d13 = MK(13), d14 = MK(14);
#undef MK
  unsigned res_i = 0;
  for (int i = 0; i < KNN; i++) {
    unsigned bv = d0, bc = 0;
#define UPD(dc, c) { if ((dc) < bv) { bv = (dc); bc = (c); } }
    UPD(d1, 1)  UPD(d2_, 2)  UPD(d3, 3)  UPD(d4, 4)  UPD(d5, 5)
    UPD(d6, 6)  UPD(d7, 7)   UPD(d8, 8)  UPD(d9, 9)  UPD(d10, 10)
    UPD(d11, 11) UPD(d12, 12) UPD(d13, 13) UPD(d14, 14)
#undef UPD
    unsigned gi = (bc << 6) + (unsigned)lane;
#pragma unroll
    for (int o = 32; o > 0; o >>= 1) {
      unsigned od = (unsigned)__shfl_xor((int)bv, o);
      unsigned oi = (unsigned)__shfl_xor((int)gi, o);
      bool take = (od < bv) || (od == bv && oi < gi);
      bv = take ? od : bv;
      gi = take ? oi : gi;
    }
    res_i = ((unsigned)lane == (unsigned)i) ? gi : res_i;
    bool wl = ((unsigned)lane == (gi & 63u));
    unsigned s = gi >> 6;
    d0  = (wl && s == 0)  ? 0xFFFFFFFFu : d0;
    d1  = (wl && s == 1)  ? 0xFFFFFFFFu : d1;
    d2_ = (wl && s == 2)  ? 0xFFFFFFFFu : d2_;
    d3  = (wl && s == 3)  ? 0xFFFFFFFFu : d3;
    d4  = (wl && s == 4)  ? 0xFFFFFFFFu : d4;
    d5  = (wl && s == 5)  ? 0xFFFFFFFFu : d5;
    d6  = (wl && s == 6)  ? 0xFFFFFFFFu : d6;
    d7  = (wl && s == 7)  ? 0xFFFFFFFFu : d7;
    d8  = (wl && s == 8)  ? 0xFFFFFFFFu : d8;
    d9  = (wl && s == 9)  ? 0xFFFFFFFFu : d9;
    d10 = (wl && s == 10) ? 0xFFFFFFFFu : d10;
    d11 = (wl && s == 11) ? 0xFFFFFFFFu : d11;
    d12 = (wl && s == 12) ? 0xFFFFFFFFu : d12;
    d13 = (wl && s == 13) ? 0xFFFFFFFFu : d13;
    d14 = (wl && s == 14) ? 0xFFFFFFFFu : d14;
  }
  if (lane < KNN)
    idx_out[((size_t)(b * TT + t)) * KNN + lane] = b * TT + (int)res_i;
}

// ---------------- wave GEMM: 16 rows x 64 cols, packed operands, no LDS ----------------
// FIX (R11 bug): block strides are NKS*512 shorts (512 per 32-k slice), not NKS*64.
template<int NKS>
__device__ __forceinline__ void wavegemm(const unsigned short* __restrict__ Apk,
                                         const unsigned short* __restrict__ Bpk,
                                         int rb, int cb0, accfrag_t (&acc)[4]) {
  const int lane = threadIdx.x & 63;
  accfrag_t z = {0.f, 0.f, 0.f, 0.f};
#pragma unroll
  for (int nt = 0; nt < 4; nt++) acc[nt] = z;
  const unsigned short* ap = Apk + ((size_t)rb * NKS * 512 + lane * 8);
  const unsigned short* bp = Bpk + ((size_t)cb0 * NKS * 512 + lane * 8);
#pragma unroll 4
  for (int ks = 0; ks < NKS; ks++) {
    bfrag_t a = *(const bfrag_t*)(ap + ks * 512);
#pragma unroll
    for (int nt = 0; nt < 4; nt++) {
      bfrag_t b = *(const bfrag_t*)(bp + (size_t)(nt * NKS + ks) * 512);
      acc[nt] = __builtin_amdgcn_mfma_f32_16x16x32_bf16(a, b, acc[nt], 0, 0, 0);
    }
  }
}

// ---------------- QKV GEMM: grid 1440 (8 scenes x 15 rbg x 12 cg), 4 waves/block ----------------
__global__ __launch_bounds__(256)
void qkv_kernel(const unsigned short* __restrict__ qkpk,
                const unsigned short* __restrict__ outpk,
                const unsigned short* __restrict__ Wl,
                const float* __restrict__ pb, int l,
                unsigned short* __restrict__ QKV) {
  int scene = blockIdx.x & 7, r = blockIdx.x >> 3;
  int rbg = r % 15, cgall = r / 15;           // cgall 0..11
  int wave = threadIdx.x >> 6, lane = threadIdx.x & 63;
  int rb = scene * 60 + rbg * 4 + wave;
  int sel = cgall >> 2, cg = cgall & 3;
  const unsigned short* A = (sel < 2) ? qkpk : outpk;
  const unsigned short* B = Wl + sel * 65536;
  const float* bias = pb + sel * 1024 + l * 256;
  accfrag_t acc[4];
  wavegemm<8>(A, B, rb, cg * 4, acc);
  int l16 = lane & 15, lq = lane >> 4;
  unsigned short* C = QKV + (size_t)sel * BT * DD;
#pragma unroll
  for (int nt = 0; nt < 4; nt++) {
    int col = cg * 64 + nt * 16 + l16;
    float bv = bias[col];
#pragma unroll
    for (int r4 = 0; r4 < 4; r4++) {
      int row = rb * 16 + lq * 4 + r4;
      C[(size_t)row * DD + col] = f2b(acc[nt][r4] + bv);
    }
  }
}

// ---------------- attention (packed output) ----------------
__global__ __launch_bounds__(256)
void attn_kernel(const unsigned short* __restrict__ QKV,
                 const int* __restrict__ idx,
                 unsigned short* __restrict__ attnpk) {
  __shared__ unsigned short kn[KNN][DD + 8];
  __shared__ unsigned short vn[KNN][DD + 8];
  __shared__ float qs[DD];
  __shared__ float att[HH][KNN];
  __shared__ int nb[KNN];
  const unsigned short* Q = QKV;
  const unsigned short* K = QKV + (size_t)BT * DD;
  const unsigned short* V = QKV + 2 * (size_t)BT * DD;
  int n = swiz_tok(blockIdx.x), tid = threadIdx.x;
  if (tid < KNN) nb[tid] = idx[n * KNN + tid];
  qs[tid] = b2f(Q[(size_t)n * DD + tid]);
  __syncthreads();
#pragma unroll
  for (int p = 0; p < 4; p++) {
    int e = p * 256 + tid;
    int r = e >> 5, c8 = (e & 31) * 8;
    int srow = nb[r];
    *(uint4*)(&kn[r][c8]) = *(const uint4*)(K + (size_t)srow * DD + c8);
    *(uint4*)(&vn[r][c8]) = *(const uint4*)(V + (size_t)srow * DD + c8);
  }
  __syncthreads();
  int h = tid >> 5, kk = tid & 31;
  float dot = 0.0f;
#pragma unroll
  for (int d = 0; d < HD; d++) dot += qs[h * HD + d] * b2f(kn[kk][h * HD + d]);
  float sc = dot * SCALE_ATT;
  float mx = sc;
#pragma unroll
  for (int o = 16; o > 0; o >>= 1) mx = fmaxf(mx, __shfl_xor(mx, o, 32));
  float ex = expf(sc - mx);
  float sm = ex;
#pragma unroll
  for (int o = 16; o > 0; o >>= 1) sm += __shfl_xor(sm, o, 32);
  att[h][kk] = ex / sm;
  __syncthreads();
  int d = kk;
  float oacc = 0.0f;
#pragma unroll
  for (int k2 = 0; k2 < KNN; k2++) oacc += att[h][k2] * b2f(vn[k2][h * HD + d]);
  attnpk[pk_addr(n, tid, 8)] = f2b(oacc);
}

// ---------------- Wo GEMM + bias + resid -> sbuf (f32) ----------------
__global__ __launch_bounds__(256)
void wo_kernel(const unsigned short* __restrict__ attnpk,
               const unsigned short* __restrict__ Wl,
               const float* __restrict__ bo,
               const float* __restrict__ out_f,
               float* __restrict__ sbuf) {
  int scene = blockIdx.x & 7, r = blockIdx.x >> 3;     // grid 480
  int rbg = r % 15, cg = r / 15;                       // cg 0..3
  int wave = threadIdx.x >> 6, lane = threadIdx.x & 63;
  int rb = scene * 60 + rbg * 4 + wave;
  accfrag_t acc[4];
  wavegemm<8>(attnpk, Wl, rb, cg * 4, acc);
  int l16 = lane & 15, lq = lane >> 4;
#pragma unroll
  for (int nt = 0; nt < 4; nt++) {
    int col = cg * 64 + nt * 16 + l16;
    float bv = bo[col];
#pragma unroll
    for (int r4 = 0; r4 < 4; r4++) {
      int row = rb * 16 + lq * 4 + r4;
      sbuf[(size_t)row * DD + col] = acc[nt][r4] + bv + out_f[(size_t)row * DD + col];
    }
  }
}

// ---------------- LN1: sbuf -> yf(=out_f, f32 rm) + xpk(=pk1, packed bf16) ----------------
__global__ __launch_bounds__(256)
void ln1_kernel(const float* __restrict__ sbuf, float* __restrict__ yf,
                unsigned short* __restrict__ xpk,
                const float* __restrict__ g, const float* __restrict__ bta) {
  int m0 = swiz_m0(blockIdx.x);                        // grid 240
  int row = m0 + (threadIdx.x >> 3), sub = threadIdx.x & 7;
  const float* src = sbuf + (size_t)row * DD + sub * 32;
  float v[32]; float s = 0.f, s2 = 0.f;
#pragma unroll
  for (int i = 0; i < 8; i++) {
    float4 t = *(const float4*)(src + i * 4);
    v[i*4+0]=t.x; v[i*4+1]=t.y; v[i*4+2]=t.z; v[i*4+3]=t.w;
    s += t.x + t.y + t.z + t.w;
    s2 += t.x*t.x + t.y*t.y + t.z*t.z + t.w*t.w;
  }
#pragma unroll
  for (int o = 1; o < 8; o <<= 1) { s += __shfl_xor(s, o); s2 += __shfl_xor(s2, o); }
  float mu = s * (1.0f/256.0f);
  float var = s2 * (1.0f/256.0f) - mu * mu;
  float rstd = 1.0f / sqrtf(fmaxf(var, 0.f) + 1e-5f);
  int c0 = sub * 32;
#pragma unroll
  for (int i = 0; i < 32; i++) v[i] = (v[i] - mu) * rstd * g[c0+i] + bta[c0+i];
  float* yo = yf + (size_t)row * DD + c0;
#pragma unroll
  for (int i = 0; i < 8; i++)
    *(float4*)(yo + i*4) = make_float4(v[i*4], v[i*4+1], v[i*4+2], v[i*4+3]);
  unsigned short* xp = xpk + (((size_t)(row >> 4) * 8 + sub) << 9) + (size_t)(row & 15) * 8;
#pragma unroll
  for (int lqc = 0; lqc < 4; lqc++)
    *(uint4*)(xp + lqc * 128) = pack8(&v[lqc * 8]);
}

// ---------------- FFN1: xpk @ W1 + b1, ReLU -> hpk (packed) ----------------
__global__ __launch_bounds__(256)
void ffn1_kernel(const unsigned short* __restrict__ xpk,
                 const unsigned short* __restrict__ Wl,
                 const float* __restrict__ b1,
                 unsigned short* __restrict__ hpk) {
  int scene = blockIdx.x & 7, r = blockIdx.x >> 3;     // grid 1920
  int rbg = r % 15, cg = r / 15;                       // cg 0..15
  int wave = threadIdx.x >> 6, lane = threadIdx.x & 63;
  int rb = scene * 60 + rbg * 4 + wave;
  accfrag_t acc[4];
  wavegemm<8>(xpk, Wl, rb, cg * 4, acc);
  int l16 = lane & 15, lq = lane >> 4;
#pragma unroll
  for (int nt = 0; nt < 4; nt++) {
    int col = cg * 64 + nt * 16 + l16;
    float bv = b1[col];
#pragma unroll
    for (int r4 = 0; r4 < 4; r4++) {
      int row = rb * 16 + lq * 4 + r4;
      hpk[pk_addr(row, col, 32)] = f2b(fmaxf(acc[nt][r4] + bv, 0.0f));
    }
  }
}

// ---------------- FFN2: hpk @ W2 + b2 -> sbuf (f32) ----------------
__global__ __launch_bounds__(256)
void ffn2_kernel(const unsigned short* __restrict__ hpk,
                 const unsigned short* __restrict__ Wl,
                 const float* __restrict__ b2,
                 float* __restrict__ sbuf) {
  int scene = blockIdx.x & 7, r = blockIdx.x >> 3;     // grid 480
  int rbg = r % 15, cg = r / 15;                       // cg 0..3
  int wave = threadIdx.x >> 6, lane = threadIdx.x & 63;
  int rb = scene * 60 + rbg * 4 + wave;
  accfrag_t acc[4];
  wavegemm<32>(hpk, Wl, rb, cg * 4, acc);
  int l16 = lane & 15, lq = lane >> 4;
#pragma unroll
  for (int nt = 0; nt < 4; nt++) {
    int col = cg * 64 + nt * 16 + l16;
    float bv = b2[col];
#pragma unroll
    for (int r4 = 0; r4 < 4; r4++) {
      int row = rb * 16 + lq * 4 + r4;
      sbuf[(size_t)row * DD + col] = acc[nt][r4] + bv;
    }
  }
}

// ---------------- LN2: (sbuf + yf) -> next-layer streams or d_out ----------------
template<bool LAST>
__global__ __launch_bounds__(256)
void ln2_kernel(const float* __restrict__ sbuf, float* __restrict__ yf,
                unsigned short* __restrict__ outpk, unsigned short* __restrict__ qkpk,
                const unsigned short* __restrict__ pe_b,
                const float* __restrict__ g, const float* __restrict__ bta,
                void* __restrict__ dout, const int* __restrict__ flag) {
  int m0 = swiz_m0(blockIdx.x);                        // grid 240
  int row = m0 + (threadIdx.x >> 3), sub = threadIdx.x & 7;
  const float* src = sbuf + (size_t)row * DD + sub * 32;
  const float* rs  = yf   + (size_t)row * DD + sub * 32;
  float v[32]; float s = 0.f, s2 = 0.f;
#pragma unroll
  for (int i = 0; i < 8; i++) {
    float4 t = *(const float4*)(src + i * 4);
    float4 u = *(const float4*)(rs + i * 4);
    float a0 = t.x + u.x, a1 = t.y + u.y, a2 = t.z + u.z, a3 = t.w + u.w;
    v[i*4+0]=a0; v[i*4+1]=a1; v[i*4+2]=a2; v[i*4+3]=a3;
    s += a0 + a1 + a2 + a3;
    s2 += a0*a0 + a1*a1 + a2*a2 + a3*a3;
  }
#pragma unroll
  for (int o = 1; o < 8; o <<= 1) { s += __shfl_xor(s, o); s2 += __shfl_xor(s2, o); }
  float mu = s * (1.0f/256.0f);
  float var = s2 * (1.0f/256.0f) - mu * mu;
  float rstd = 1.0f / sqrtf(fmaxf(var, 0.f) + 1e-5f);
  int c0 = sub * 32;
#pragma unroll
  for (int i = 0; i < 32; i++) v[i] = (v[i] - mu) * rstd * g[c0+i] + bta[c0+i];
  if (!LAST) {
    float* yo = yf + (size_t)row * DD + c0;
#pragma unroll
    for (int i = 0; i < 8; i++)
      *(float4*)(yo + i*4) = make_float4(v[i*4], v[i*4+1], v[i*4+2], v[i*4+3]);
    unsigned short* op = outpk + (((size_t)(row >> 4) * 8 + sub) << 9) + (size_t)(row & 15) * 8;
#pragma unroll
    for (int lqc = 0; lqc < 4; lqc++)
      *(uint4*)(op + lqc * 128) = pack8(&v[lqc * 8]);
    const unsigned short* pp = pe_b + (size_t)row * DD + c0;
    float q[32];
#pragma unroll
    for (int i = 0; i < 32; i++) q[i] = v[i] + b2f(pp[i]);
    unsigned short* qp = qkpk + (((size_t)(row >> 4) * 8 + sub) << 9) + (size_t)(row & 15) * 8;
#pragma unroll
    for (int lqc = 0; lqc < 4; lqc++)
      *(uint4*)(qp + lqc * 128) = pack8(&q[lqc * 8]);
  } else {
    int b = row / TT, t = row - b * TT;
    size_t o;
    if (t < MTOK)             o = (size_t)(b * MTOK + t) * DD + c0;
    else if (t < MTOK + NTOK) o = (size_t)BB * MTOK * DD + (size_t)(b * NTOK + (t - MTOK)) * DD + c0;
    else                      o = (size_t)BB * MTOK * DD + (size_t)BB * NTOK * DD
                                + (size_t)(b * LTOK + (t - MTOK - NTOK)) * DD + c0;
    if (*flag) {
      unsigned short* dp = (unsigned short*)dout + o;
#pragma unroll
      for (int lqc = 0; lqc < 4; lqc++)
        *(uint4*)(dp + lqc * 8) = pack8(&v[lqc * 8]);
    } else {
      float* dp = (float*)dout + o;
#pragma unroll
      for (int i = 0; i < 8; i++)
        *(float4*)(dp + i*4) = make_float4(v[i*4], v[i*4+1], v[i*4+2], v[i*4+3]);
    }
  }
}

// ---------------- launcher ----------------
extern "C" void kernel_launch(void* const* d_in, const int* in_sizes, int n_in,
                              void* d_out, int out_size, void* d_ws, size_t ws_size,
                              hipStream_t stream) {
  const void* map_tok   = d_in[0];
  const void* agent_tok = d_in[1];
  const void* light_tok = d_in[2];
  const void* map_pos   = d_in[3];
  const void* agent_pos = d_in[4];
  const void* light_pos = d_in[5];
  const void* Wq  = d_in[9];
  const void* bq  = d_in[10];
  const void* Wk  = d_in[11];
  const void* bk  = d_in[12];
  const void* Wv  = d_in[13];
  const void* bv  = d_in[14];
  const void* Wo  = d_in[15];
  const void* bo  = d_in[16];
  const void* W1  = d_in[17];
  const void* b1  = d_in[18];
  const void* W2  = d_in[19];
  const void* b2  = d_in[20];
  const void* ln1s = d_in[21];
  const void* ln1b = d_in[22];
  const void* ln2s = d_in[23];
  const void* ln2b = d_in[24];

  size_t off = 0;
  char* base = (char*)d_ws;
  auto take = [&](size_t bytes) { char* p = base + off; off += (bytes + 255) & ~(size_t)255; return (void*)p; };
  int*   flag  = (int*)take(256);
  float* posf  = (float*)take((size_t)BT * 2 * 4);
  float* pbuf  = (float*)take((size_t)FB_TOTAL * 4);
  unsigned short* pe_b = (unsigned short*)take((size_t)BT * DD * 2);
  float* out_f = (float*)take((size_t)BT * DD * 4);   // residual stream; LN1 writes y here
  unsigned short* pk1  = (unsigned short*)take((size_t)BT * DD * 2);  // outpk / xpk (aliased in time)
  unsigned short* qkpk = (unsigned short*)take((size_t)BT * DD * 2);
  unsigned short* QKV  = (unsigned short*)take((size_t)3 * BT * DD * 2);
  unsigned short* attnpk = (unsigned short*)take((size_t)BT * DD * 2);
  float* sbuf  = (float*)take((size_t)BT * DD * 4);   // wo-out then ffn2-out
  unsigned short* hpk  = (unsigned short*)take((size_t)BT * FFD * 2);
  int* idxb = (int*)take((size_t)BT * KNN * 4);
  unsigned short* Wqkvpk = (unsigned short*)take((size_t)NLAYERS * 3 * DD * DD * 2);
  unsigned short* Wopk   = (unsigned short*)take((size_t)NLAYERS * DD * DD * 2);
  unsigned short* W1pk   = (unsigned short*)take((size_t)NLAYERS * DD * FFD * 2);
  unsigned short* W2pk   = (unsigned short*)take((size_t)NLAYERS * DD * FFD * 2);

  detect_kernel<<<1, 256, 0, stream>>>(map_tok, flag);
  ParamSrc ps; ps.p[0]=bq; ps.p[1]=bk; ps.p[2]=bv; ps.p[3]=bo; ps.p[4]=b1;
  ps.p[5]=b2; ps.p[6]=ln1s; ps.p[7]=ln1b; ps.p[8]=ln2s; ps.p[9]=ln2b;
  ps.p[10]=map_pos; ps.p[11]=agent_pos; ps.p[12]=light_pos;
  conv_misc_kernel<<<BB + (FB_TOTAL + 255) / 256, 256, 0, stream>>>(ps, flag, pbuf, posf);

  PackSrc pw; pw.s[0]=Wq; pw.s[1]=Wk; pw.s[2]=Wv; pw.s[3]=Wo; pw.s[4]=W1; pw.s[5]=W2;
  packW_kernel<<<12288, 256, 0, stream>>>(pw, flag, Wqkvpk, Wopk, W1pk, W2pk);

  prep_kernel<<<BT, 256, 0, stream>>>(map_tok, agent_tok, light_tok, posf, flag,
                                      pe_b, out_f, pk1, qkpk);
  knn_kernel<<<1920, 256, 0, stream>>>(posf, idxb);

  for (int l = 0; l < NLAYERS; l++) {
    qkv_kernel<<<1440, 256, 0, stream>>>(qkpk, pk1, Wqkvpk + (size_t)l * 3 * 65536,
                                         pbuf, l, QKV);
    attn_kernel<<<BT, 256, 0, stream>>>(QKV, idxb, attnpk);
    wo_kernel<<<480, 256, 0, stream>>>(attnpk, Wopk + (size_t)l * 65536,
                                       pbuf + FB_BO + l * 256, out_f, sbuf);
    ln1_kernel<<<240, 256, 0, stream>>>(sbuf, out_f, pk1,
                                        pbuf + FB_LN1S + l * 256, pbuf + FB_LN1B + l * 256);
    ffn1_kernel<<<1920, 256, 0, stream>>>(pk1, W1pk + (size_t)l * 262144,
                                          pbuf + FB_B1 + l * 1024, hpk);
    ffn2_kernel<<<480, 256, 0, stream>>>(hpk, W2pk + (size_t)l * 262144,
                                         pbuf + FB_B2 + l * 256, sbuf);
    if (l < NLAYERS - 1)
      ln2_kernel<false><<<240, 256, 0, stream>>>(sbuf, out_f, pk1, qkpk, pe_b,
                                                 pbuf + FB_LN2S + l * 256, pbuf + FB_LN2B + l * 256,
                                                 d_out, flag);
    else
      ln2_kernel<true><<<240, 256, 0, stream>>>(sbuf, out_f, pk1, qkpk, pe_b,
                                                pbuf + FB_LN2S + l * 256, pbuf + FB_LN2B + l * 256,
                                                d_out, flag);
  }
}